// Round 6
// baseline (195.433 us; speedup 1.0000x reference)
//
#include <hip/hip_runtime.h>

// Diversity2: mean(0.3 * pearson_corr(softmax(o1/T), softmax(o2/T), axis=1))
//
// Identities:
//  (1) corr is invariant to per-row positive scaling and shift -> softmax
//      normalization and max-subtraction drop out: corr(p1,p2) ==
//      corr(exp(o1/T), exp(o2/T)).
//  (2) shift again: x = exp(o/T) - 1 (exact Sterbenz subtraction, exp in
//      [0.78,1.32]) centers x near 0 so fp32 accumulation of
//      {Sx,Sy,Sxx,Syy,Sxy} has no catastrophic cancellation
//      (Sxx ~ 2.5 vs (Sx)^2/C ~ 0.003). fp64 only in the per-row epilogue
//      and the final mean.
//
// Round-6: round-5's stage1 VERBATIM (best measured: 100.3 us; four
// independent structures converge at ~100 -> stream-limited at ~5.7 TB/s
// aggregate read) + ONE delta: fuse the final reduction into the same
// kernel (r3 mechanism: partial -> ws, release counter, last block reduces
// 2048 partials in deterministic order), keeping the 2048-block grid.
// This removes the second dispatch (~6-9 us of launch latency + 1-block
// kernel). r3's regression is attributed to its 512-block one-round grid,
// not fusion; this round is the clean A/B for that attribution.
//
// Tail: row = 1000 floats = 250 float4; chunk k=3 valid lanes<58 only.
// Lanes >=58 read float4 index 0 (always in-bounds), inputs zeroed at
// consume: exp(0)-1 == 0 contributes nothing to any sum.

#define N_ROWS  65536
#define N_C     1000
#define NBLOCKS 2048
#define WPB     4

__global__ __launch_bounds__(256) void div2_fused(
        const float* __restrict__ o1, const float* __restrict__ o2,
        double* __restrict__ ws, unsigned int* __restrict__ cnt,
        float* __restrict__ out) {
    const int wave = threadIdx.x >> 6;
    const int lane = threadIdx.x & 63;
    const int gw   = blockIdx.x * WPB + wave;
    const int nw   = NBLOCKS * WPB;
    const int i3   = (lane < 58) ? (192 + lane) : 0;   // clamped chunk-3 idx
    constexpr float INV_T = 1.0f / 20.0f;

    double acc = 0.0;
    #pragma unroll 1
    for (long row = gw; row < (long)N_ROWS; row += nw) {
        const float4* A = reinterpret_cast<const float4*>(o1 + row * (long)N_C);
        const float4* B = reinterpret_cast<const float4*>(o2 + row * (long)N_C);
        // all 8 loads of the row-pair issued before any use
        float4 a0 = A[lane];
        float4 a1 = A[64 + lane];
        float4 a2 = A[128 + lane];
        float4 a3 = A[i3];
        float4 b0 = B[lane];
        float4 b1 = B[64 + lane];
        float4 b2 = B[128 + lane];
        float4 b3 = B[i3];

        float sx = 0.f, sy = 0.f, sxx = 0.f, syy = 0.f, sxy = 0.f;
        float va[16] = {a0.x, a0.y, a0.z, a0.w, a1.x, a1.y, a1.z, a1.w,
                        a2.x, a2.y, a2.z, a2.w, a3.x, a3.y, a3.z, a3.w};
        float vb[16] = {b0.x, b0.y, b0.z, b0.w, b1.x, b1.y, b1.z, b1.w,
                        b2.x, b2.y, b2.z, b2.w, b3.x, b3.y, b3.z, b3.w};
        const bool tail_ok = (lane < 58);
        #pragma unroll
        for (int e = 0; e < 16; ++e) {
            const bool ok = (e < 12) || tail_ok;     // compile-time e
            float fa = ok ? va[e] : 0.0f;            // static index (rule #20)
            float fb = ok ? vb[e] : 0.0f;
            float x = __expf(fa * INV_T) - 1.0f;
            float y = __expf(fb * INV_T) - 1.0f;
            sx += x;  sy += y;
            sxx = fmaf(x, x, sxx);
            syy = fmaf(y, y, syy);
            sxy = fmaf(x, y, sxy);
        }
        #pragma unroll
        for (int off = 32; off; off >>= 1) {
            sx  += __shfl_xor(sx,  off, 64);
            sy  += __shfl_xor(sy,  off, 64);
            sxx += __shfl_xor(sxx, off, 64);
            syy += __shfl_xor(syy, off, 64);
            sxy += __shfl_xor(sxy, off, 64);
        }
        constexpr double invC = 1.0 / (double)N_C;
        double dx = (double)sx, dy = (double)sy;
        double num = (double)sxy - dx * dy * invC;
        double vx  = (double)sxx - dx * dx * invC;
        double vy  = (double)syy - dy * dy * invC;
        acc += num / sqrt(vx * vy);
    }

    // ---- block combine ----
    __shared__ double dred[WPB];
    __shared__ int slast;
    if (lane == 0) dred[wave] = acc;
    __syncthreads();
    if (threadIdx.x == 0) {
        ws[blockIdx.x] = dred[0] + dred[1] + dred[2] + dred[3];
        unsigned int old = __hip_atomic_fetch_add(cnt, 1u, __ATOMIC_ACQ_REL,
                                                  __HIP_MEMORY_SCOPE_AGENT);
        slast = (old == NBLOCKS - 1);
    }
    __syncthreads();

    // ---- last finishing block: reduce all 2048 partials (fixed order) ----
    if (slast) {
        const int t = threadIdx.x;
        double s = 0.0;
        #pragma unroll
        for (int i = 0; i < NBLOCKS / 256; ++i)
            s += __hip_atomic_load(&ws[t + i * 256], __ATOMIC_RELAXED,
                                   __HIP_MEMORY_SCOPE_AGENT);
        #pragma unroll
        for (int off = 32; off; off >>= 1) s += __shfl_xor(s, off, 64);
        if (lane == 0) dred[wave] = s;
        __syncthreads();
        if (t == 0)
            out[0] = (float)((dred[0] + dred[1] + dred[2] + dred[3]) *
                             (0.3 / (double)N_ROWS));
    }
}

extern "C" void kernel_launch(void* const* d_in, const int* in_sizes, int n_in,
                              void* d_out, int out_size, void* d_ws, size_t ws_size,
                              hipStream_t stream) {
    const float* o1 = (const float*)d_in[0];
    const float* o2 = (const float*)d_in[1];
    // d_in[2] (targets) is unused by the reference.
    float* out = (float*)d_out;
    double* ws = (double*)d_ws;                        // 2048 block partials
    unsigned int* cnt = (unsigned int*)((char*)d_ws + NBLOCKS * sizeof(double));

    // zero the completion counter each call (graph-capturable async memset)
    hipMemsetAsync((void*)cnt, 0, sizeof(unsigned int), stream);

    div2_fused<<<NBLOCKS, 256, 0, stream>>>(o1, o2, ws, cnt, out);
}

// Round 7
// 96.095 us; speedup vs baseline: 2.0338x; 2.0338x over previous
//
#include <hip/hip_runtime.h>

// Diversity2: mean(0.3 * pearson_corr(softmax(o1/T), softmax(o2/T), axis=1))
//
// Identities:
//  (1) corr invariant to per-row positive scale+shift -> softmax drops out:
//      corr(p1,p2) == corr(exp(o1/T), exp(o2/T)).
//  (2) x = exp(o/T) - 1 (exact Sterbenz, exp in [0.78,1.32]) centers x near 0
//      -> fp32 accumulation of {Sx,Sy,Sxx,Syy,Sxy} has no catastrophic
//      cancellation. fp64 only in per-row epilogue + final mean.
//
// Round-7: r5 (best: 100.3 us) + ONE clean delta: explicit 2-row register
// pipeline in FLAT code (16 named float4 locals, no structs/lambdas/refs,
// statically peeled last iteration -> no conditional loads, no extra traffic).
// r4 tried this but codegen (struct-by-ref + lambda, VGPR=56) never kept two
// rows in flight -- invalid test. Two-kernel finish (r6 post-mortem: 2048
// serialized ACQ_REL RMWs on one cacheline cost +95 us; single-counter fused
// finish is dead -- Guideline 12).
//
// Pre-committed read: <=94 us -> latency residual real; ~97-104 us with
// unchanged counters -> third independent in-flight-depth mechanism neutral
// -> read-path roofline, declare next round.
//
// Tail: row = 1000 floats = 250 float4; chunk 3 valid lanes<58. Lanes >=58
// read float4 index 0 (in-bounds), inputs zeroed at consume (exp(0)-1 == 0).

#define N_ROWS  65536
#define N_C     1000
#define NBLOCKS 2048
#define WPB     4
#define RPW     8                 // rows per wave; row stride = 8192
#define RSTEP   (NBLOCKS * WPB)   // 8192

__device__ __forceinline__ const float4* rp(const float* o, int row) {
    return reinterpret_cast<const float4*>(o + (long)row * N_C);
}

__device__ __forceinline__ void accum_row(
        float4 a0, float4 a1, float4 a2, float4 a3,
        float4 b0, float4 b1, float4 b2, float4 b3,
        bool tail_ok, double& acc) {
    constexpr float INV_T = 1.0f / 20.0f;
    float sx = 0.f, sy = 0.f, sxx = 0.f, syy = 0.f, sxy = 0.f;
    float va[16] = {a0.x, a0.y, a0.z, a0.w, a1.x, a1.y, a1.z, a1.w,
                    a2.x, a2.y, a2.z, a2.w, a3.x, a3.y, a3.z, a3.w};
    float vb[16] = {b0.x, b0.y, b0.z, b0.w, b1.x, b1.y, b1.z, b1.w,
                    b2.x, b2.y, b2.z, b2.w, b3.x, b3.y, b3.z, b3.w};
    #pragma unroll
    for (int e = 0; e < 16; ++e) {
        const bool ok = (e < 12) || tail_ok;    // compile-time e
        float fa = ok ? va[e] : 0.0f;           // static index (rule #20)
        float fb = ok ? vb[e] : 0.0f;
        float x = __expf(fa * INV_T) - 1.0f;
        float y = __expf(fb * INV_T) - 1.0f;
        sx += x;  sy += y;
        sxx = fmaf(x, x, sxx);
        syy = fmaf(y, y, syy);
        sxy = fmaf(x, y, sxy);
    }
    #pragma unroll
    for (int off = 32; off; off >>= 1) {
        sx  += __shfl_xor(sx,  off, 64);
        sy  += __shfl_xor(sy,  off, 64);
        sxx += __shfl_xor(sxx, off, 64);
        syy += __shfl_xor(syy, off, 64);
        sxy += __shfl_xor(sxy, off, 64);
    }
    constexpr double invC = 1.0 / (double)N_C;
    double dx = (double)sx, dy = (double)sy;
    double num = (double)sxy - dx * dy * invC;
    double vx  = (double)sxx - dx * dx * invC;
    double vy  = (double)syy - dy * dy * invC;
    acc += num / sqrt(vx * vy);
}

__global__ __launch_bounds__(256) void div2_stage1(
        const float* __restrict__ o1, const float* __restrict__ o2,
        double* __restrict__ ws) {
    const int wave = threadIdx.x >> 6;
    const int lane = threadIdx.x & 63;
    const int gw   = blockIdx.x * WPB + wave;
    const int i3   = (lane < 58) ? (192 + lane) : 0;   // clamped chunk-3 idx
    const bool tail_ok = (lane < 58);

    int r = gw;
    double acc = 0.0;

    // prologue: load row-pair r into set P
    const float4* A = rp(o1, r);
    const float4* B = rp(o2, r);
    float4 pa0 = A[lane], pa1 = A[64 + lane], pa2 = A[128 + lane], pa3 = A[i3];
    float4 pb0 = B[lane], pb1 = B[64 + lane], pb2 = B[128 + lane], pb3 = B[i3];

    // steady state: rows r..r+5 (3 iterations x 2 rows), always prefetching
    #pragma unroll 1
    for (int p = 0; p < RPW - 2; p += 2) {
        const float4* A1 = rp(o1, r + RSTEP);
        const float4* B1 = rp(o2, r + RSTEP);
        float4 qa0 = A1[lane], qa1 = A1[64 + lane], qa2 = A1[128 + lane], qa3 = A1[i3];
        float4 qb0 = B1[lane], qb1 = B1[64 + lane], qb2 = B1[128 + lane], qb3 = B1[i3];
        accum_row(pa0, pa1, pa2, pa3, pb0, pb1, pb2, pb3, tail_ok, acc);

        const float4* A2 = rp(o1, r + 2 * RSTEP);
        const float4* B2 = rp(o2, r + 2 * RSTEP);
        pa0 = A2[lane]; pa1 = A2[64 + lane]; pa2 = A2[128 + lane]; pa3 = A2[i3];
        pb0 = B2[lane]; pb1 = B2[64 + lane]; pb2 = B2[128 + lane]; pb3 = B2[i3];
        accum_row(qa0, qa1, qa2, qa3, qb0, qb1, qb2, qb3, tail_ok, acc);

        r += 2 * RSTEP;
    }

    // epilogue: rows r (in P) and r+RSTEP (prefetch now, compute after P)
    {
        const float4* A1 = rp(o1, r + RSTEP);
        const float4* B1 = rp(o2, r + RSTEP);
        float4 qa0 = A1[lane], qa1 = A1[64 + lane], qa2 = A1[128 + lane], qa3 = A1[i3];
        float4 qb0 = B1[lane], qb1 = B1[64 + lane], qb2 = B1[128 + lane], qb3 = B1[i3];
        accum_row(pa0, pa1, pa2, pa3, pb0, pb1, pb2, pb3, tail_ok, acc);
        accum_row(qa0, qa1, qa2, qa3, qb0, qb1, qb2, qb3, tail_ok, acc);
    }

    __shared__ double dred[WPB];
    if (lane == 0) dred[wave] = acc;
    __syncthreads();
    if (threadIdx.x == 0)
        ws[blockIdx.x] = dred[0] + dred[1] + dred[2] + dred[3];
}

__global__ __launch_bounds__(256) void div2_stage2(
        const double* __restrict__ ws, int n, float* __restrict__ out) {
    double s = 0.0;
    for (int i = threadIdx.x; i < n; i += 256) s += ws[i];
    #pragma unroll
    for (int off = 32; off; off >>= 1) s += __shfl_xor(s, off, 64);
    __shared__ double lds[4];
    const int wave = threadIdx.x >> 6;
    const int lane = threadIdx.x & 63;
    if (lane == 0) lds[wave] = s;
    __syncthreads();
    if (threadIdx.x == 0) {
        double t = lds[0] + lds[1] + lds[2] + lds[3];
        out[0] = (float)(t * (0.3 / (double)N_ROWS));
    }
}

extern "C" void kernel_launch(void* const* d_in, const int* in_sizes, int n_in,
                              void* d_out, int out_size, void* d_ws, size_t ws_size,
                              hipStream_t stream) {
    const float* o1 = (const float*)d_in[0];
    const float* o2 = (const float*)d_in[1];
    // d_in[2] (targets) is unused by the reference.
    float* out = (float*)d_out;
    double* ws = (double*)d_ws;   // 2048 doubles = 16 KB

    div2_stage1<<<NBLOCKS, 256, 0, stream>>>(o1, o2, ws);
    div2_stage2<<<1, 256, 0, stream>>>(ws, NBLOCKS, out);
}